// Round 3
// baseline (62.672 us; speedup 1.0000x reference)
//
#include <hip/hip_runtime.h>

// out[i, 7n+o, m] = sum_{j,k} x[j, 7n+o+k-1, m] * W[i,j,k], taps clipped to o+k-1 in [0,7)
// x: (48,56,56) f32, W: (192,48,3) f32, out: (192,56,56) f32
//
// R3: split-j(8) + LDS reduce. 128-thread block = 16 columns x 8 j-segments.
// 1344 blocks (5.25/CU), 2688 waves. Each block has a uniform output channel i
// (112 cols per channel / 16 cols per block = 7 blocks per channel, exact).

#define CH_IN 48
#define CH_OUT 192
#define HW 56
#define SP 3136   // 56*56
#define OB 7      // rows per block
#define M4 14     // float4 chunks per 56-wide row
#define COLS 112                  // columns per output channel (8*14)
#define NCOL (CH_OUT * COLS)      // 21504 columns total
#define SEGS 8
#define JSEG (CH_IN / SEGS)       // 6 input channels per segment
#define BCOL 16                   // columns per block

__device__ __forceinline__ void fma4(float4& a, float s, const float4& b) {
    a.x += s * b.x; a.y += s * b.y; a.z += s * b.z; a.w += s * b.w;
}
__device__ __forceinline__ void add4(float4& a, const float4& b) {
    a.x += b.x; a.y += b.y; a.z += b.z; a.w += b.w;
}

__global__ __launch_bounds__(128) void conv_split8_kernel(const float* __restrict__ x,
                                                          const float* __restrict__ W,
                                                          float* __restrict__ out) {
    __shared__ float4 lds[SEGS][OB][BCOL];   // 14 KB

    const int c   = threadIdx.x & (BCOL - 1);   // column within block
    const int seg = threadIdx.x / BCOL;         // j-segment
    const int col = blockIdx.x * BCOL + c;      // global column

    const int i   = col / COLS;                 // output channel (uniform per block)
    const int rem = col % COLS;
    const int n   = rem / M4;                   // 7-row block
    const int m4  = rem % M4;                   // float4 index along width

    const float* xcol = x + seg * (JSEG * SP) + n * (OB * HW) + m4 * 4;
    const float* wrow = W + i * (CH_IN * 3) + seg * (JSEG * 3);

    float4 acc[OB];
#pragma unroll
    for (int o = 0; o < OB; ++o) acc[o] = make_float4(0.f, 0.f, 0.f, 0.f);

#pragma unroll
    for (int j = 0; j < JSEG; ++j) {
        const float w0 = wrow[j * 3 + 0];
        const float w1 = wrow[j * 3 + 1];
        const float w2 = wrow[j * 3 + 2];

        const float* xj = xcol + j * SP;
        float4 xv[OB];
#pragma unroll
        for (int o = 0; o < OB; ++o)
            xv[o] = *reinterpret_cast<const float4*>(xj + o * HW);

#pragma unroll
        for (int o = 0; o < OB; ++o) {
            if (o > 0)      fma4(acc[o], w0, xv[o - 1]);  // k=0 tap
            fma4(acc[o], w1, xv[o]);                      // k=1 tap
            if (o < OB - 1) fma4(acc[o], w2, xv[o + 1]);  // k=2 tap
        }
    }

#pragma unroll
    for (int o = 0; o < OB; ++o) lds[seg][o][c] = acc[o];
    __syncthreads();

    // 112 outputs (7 rows x 16 cols) per block; threads 0..111 reduce 8 segments each.
    const int t = threadIdx.x;
    if (t < OB * BCOL) {
        const int o  = t / BCOL;
        const int cc = t & (BCOL - 1);
        float4 s = lds[0][o][cc];
#pragma unroll
        for (int sgi = 1; sgi < SEGS; ++sgi) add4(s, lds[sgi][o][cc]);

        const int col2 = blockIdx.x * BCOL + cc;
        const int i2   = col2 / COLS;
        const int rem2 = col2 % COLS;
        const int n2   = rem2 / M4;
        const int m42  = rem2 % M4;
        *reinterpret_cast<float4*>(out + i2 * SP + n2 * (OB * HW) + o * HW + m42 * 4) = s;
    }
}

extern "C" void kernel_launch(void* const* d_in, const int* in_sizes, int n_in,
                              void* d_out, int out_size, void* d_ws, size_t ws_size,
                              hipStream_t stream) {
    const float* x = (const float*)d_in[0];
    const float* W = (const float*)d_in[1];
    float* out = (float*)d_out;

    const int grid = NCOL / BCOL;  // 1344 blocks x 128 threads
    conv_split8_kernel<<<grid, 128, 0, stream>>>(x, W, out);
}